// Round 5
// baseline (796.377 us; speedup 1.0000x reference)
//
#include <hip/hip_runtime.h>

typedef unsigned short u16;
typedef unsigned int   u32;
typedef __attribute__((ext_vector_type(8))) short bf16x8;
typedef __attribute__((ext_vector_type(4))) float f32x4;

#define MFMA_BF16 __builtin_amdgcn_mfma_f32_16x16x32_bf16

__device__ __forceinline__ float bf2f(u16 v) {
    u32 x = ((u32)v) << 16;
    return __builtin_bit_cast(float, x);
}
__device__ __forceinline__ float bflo(u32 u) { return __builtin_bit_cast(float, u << 16); }
__device__ __forceinline__ float bfhi(u32 u) { return __builtin_bit_cast(float, u & 0xffff0000u); }
__device__ __forceinline__ u16 f2bf(float f) {
    u32 x = __builtin_bit_cast(u32, f);
    u32 r = (x + 0x7fffu + ((x >> 16) & 1u)) >> 16;
    return (u16)r;
}
__device__ __forceinline__ float mishf(float x) {
    float p = 1.f + __expf(x);
    float q = p * p;
    float r = (q - 1.f) / (q + 1.f);
    return (x > 20.f) ? x : x * r;
}

// ---------------------------------------------------------------------------
// MFMA GEMM: C[M,N] = bf16( A[M,K] @ W[K,N] * scale ), fp32 in, bf16 out.
// Tile 128M x 64N, K-step 32, 256 thr. M % 128 == 0, N = 1024, K = 256.
// ---------------------------------------------------------------------------
__global__ __launch_bounds__(256) void gemm_mfma(
    const float* __restrict__ A, const float* __restrict__ W, u16* __restrict__ C,
    int M, int N, int K, float scale)
{
    __shared__ u16 As[128 * 40];
    __shared__ u16 Bf[4 * 64 * 8];

    const int tid = threadIdx.x;
    const int lane = tid & 63, wv = tid >> 6;
    const int qd = lane >> 4, ln = lane & 15;
    const int m0 = blockIdx.y * 128, n0 = blockIdx.x * 64;

    f32x4 acc[2][4];
#pragma unroll
    for (int a = 0; a < 2; ++a)
#pragma unroll
        for (int nt = 0; nt < 4; ++nt) acc[a][nt] = (f32x4){0.f, 0.f, 0.f, 0.f};

    for (int k0 = 0; k0 < K; k0 += 32) {
        {
            int r = tid >> 1, kh = (tid & 1) * 16;
            const float* ap = A + (size_t)(m0 + r) * K + k0 + kh;
            float4 a0 = ((const float4*)ap)[0];
            float4 a1 = ((const float4*)ap)[1];
            float4 a2 = ((const float4*)ap)[2];
            float4 a3 = ((const float4*)ap)[3];
            uint4 p0, p1;
            p0.x = (u32)f2bf(a0.x) | ((u32)f2bf(a0.y) << 16);
            p0.y = (u32)f2bf(a0.z) | ((u32)f2bf(a0.w) << 16);
            p0.z = (u32)f2bf(a1.x) | ((u32)f2bf(a1.y) << 16);
            p0.w = (u32)f2bf(a1.z) | ((u32)f2bf(a1.w) << 16);
            p1.x = (u32)f2bf(a2.x) | ((u32)f2bf(a2.y) << 16);
            p1.y = (u32)f2bf(a2.z) | ((u32)f2bf(a2.w) << 16);
            p1.z = (u32)f2bf(a3.x) | ((u32)f2bf(a3.y) << 16);
            p1.w = (u32)f2bf(a3.z) | ((u32)f2bf(a3.w) << 16);
            *(uint4*)&As[r * 40 + kh]     = p0;
            *(uint4*)&As[r * 40 + kh + 8] = p1;
        }
        {
            int nt = tid >> 6, q = (tid >> 4) & 3, nn = tid & 15;
            const float* wp = W + (size_t)(k0 + q * 8) * N + n0 + nt * 16 + nn;
            bf16x8 v;
#pragma unroll
            for (int j = 0; j < 8; ++j) v[j] = (short)f2bf(wp[(size_t)j * N]);
            *(bf16x8*)&Bf[tid * 8] = v;
        }
        __syncthreads();
        bf16x8 af0 = *(const bf16x8*)&As[(wv * 32 + ln) * 40 + qd * 8];
        bf16x8 af1 = *(const bf16x8*)&As[(wv * 32 + 16 + ln) * 40 + qd * 8];
#pragma unroll
        for (int nt = 0; nt < 4; ++nt) {
            bf16x8 bfr = *(const bf16x8*)&Bf[(nt * 64 + lane) * 8];
            acc[0][nt] = MFMA_BF16(af0, bfr, acc[0][nt], 0, 0, 0);
            acc[1][nt] = MFMA_BF16(af1, bfr, acc[1][nt], 0, 0, 0);
        }
        __syncthreads();
    }
#pragma unroll
    for (int a = 0; a < 2; ++a)
#pragma unroll
        for (int nt = 0; nt < 4; ++nt)
#pragma unroll
            for (int r = 0; r < 4; ++r)
                C[(size_t)(m0 + wv * 32 + a * 16 + qd * 4 + r) * N + n0 + nt * 16 + ln] =
                    f2bf(acc[a][nt][r] * scale);
}

// ---------------------------------------------------------------------------
// transpose cv[b*512+j][1024 ch] -> cvT[(b*1024+ch)*512 + j]. 64x64 tiles.
// ---------------------------------------------------------------------------
__global__ __launch_bounds__(256) void transpose_cv(
    const u16* __restrict__ cv, u16* __restrict__ cvT)
{
    __shared__ u16 T[64 * 80];
    const int tid = threadIdx.x;
    const int ct = blockIdx.x * 64, jt = blockIdx.y * 64, b = blockIdx.z;
    {
        int j_l = tid >> 2, seg = tid & 3;
        const u16* src = cv + (size_t)(b * 512 + jt + j_l) * 1024 + ct + seg * 16;
        uint4 v0 = ((const uint4*)src)[0];
        uint4 v1 = ((const uint4*)src)[1];
        u16* tp = &T[seg * 16 * 80 + j_l];
        tp[0*80] = (u16)(v0.x & 0xffff); tp[1*80] = (u16)(v0.x >> 16);
        tp[2*80] = (u16)(v0.y & 0xffff); tp[3*80] = (u16)(v0.y >> 16);
        tp[4*80] = (u16)(v0.z & 0xffff); tp[5*80] = (u16)(v0.z >> 16);
        tp[6*80] = (u16)(v0.w & 0xffff); tp[7*80] = (u16)(v0.w >> 16);
        tp[8*80] = (u16)(v1.x & 0xffff); tp[9*80] = (u16)(v1.x >> 16);
        tp[10*80] = (u16)(v1.y & 0xffff); tp[11*80] = (u16)(v1.y >> 16);
        tp[12*80] = (u16)(v1.z & 0xffff); tp[13*80] = (u16)(v1.z >> 16);
        tp[14*80] = (u16)(v1.w & 0xffff); tp[15*80] = (u16)(v1.w >> 16);
    }
    __syncthreads();
    {
        int ch_l = tid >> 2, sg = tid & 3;
        u16* dst = cvT + (size_t)(b * 1024 + ct + ch_l) * 512 + jt + sg * 16;
        ((uint4*)dst)[0] = *(const uint4*)&T[ch_l * 80 + sg * 16];
        ((uint4*)dst)[1] = *(const uint4*)&T[ch_l * 80 + sg * 16 + 8];
    }
}

// ---------------------------------------------------------------------------
// Prep: WoT[col][k] bf16; W1/W2 swizzled to MFMA B-frag order (global,
// L2-resident, read per-MFMA by attn4).
// ---------------------------------------------------------------------------
__global__ __launch_bounds__(256) void prep(
    const float* __restrict__ Wo, const float* __restrict__ W1, const float* __restrict__ W2,
    u16* __restrict__ WoT, u16* __restrict__ w1b, u16* __restrict__ w2b)
{
    const int bb = blockIdx.x, t = threadIdx.x;
    if (bb < 256) {
#pragma unroll
        for (int kk = 0; kk < 4; ++kk)
            WoT[(size_t)t * 1024 + bb * 4 + kk] = f2bf(Wo[(size_t)(bb * 4 + kk) * 256 + t]);
    } else {
        for (int u = 0; u < 32; ++u) {        // W1: frag f = ks*8+nt
            int idx = t + 256 * u;
            int j = idx & 7, lane = (idx >> 3) & 63, f = idx >> 9;
            int n = lane & 15, q = lane >> 4, ntc = f & 7, ks = f >> 3;
            w1b[idx] = f2bf(W1[(ks * 32 + q * 8 + j) * 128 + ntc * 16 + n]);
        }
        for (int u = 0; u < 32; ++u) {        // W2: frag f = ks*4+ot
            int idx = t + 256 * u;
            int j = idx & 7, lane = (idx >> 3) & 63, f = idx >> 9;
            int n = lane & 15, q = lane >> 4, ot = f & 3, ks = f >> 2;
            w2b[idx] = f2bf(W2[(ks * 32 + q * 8 + j) * 64 + ot * 16 + n]);
        }
    }
}

// ---------------------------------------------------------------------------
// attn4: block = (b, i-tile 16, j-quarter 128), XCD-swizzled so b-pairs pin
// to one XCD's L2. 8 passes of 16 j. P1 sim MFMA -> ES; P2 MLP MFMA chain,
// E -> padded Estage (LDS); P3 PV via MFMA (A=Estage, B=cvT 16B/lane), AGPR
// accumulators. dn/dd in registers, shfl-reduced at the end.
// Partial per (b,it,jq): [out 16x1024][denom 16x64][dis 16x96] fp32.
// ---------------------------------------------------------------------------
__global__ __launch_bounds__(256, 2) void attn4(
    const u16* __restrict__ qk,      // [2048][1024] bf16 (scale folded)
    const u16* __restrict__ cqk,     // [8192][1024] bf16
    const u16* __restrict__ cvT,     // [16][1024][512] bf16
    const float* __restrict__ bde,   // [16][512][128][32]
    const float* __restrict__ bdis,  // [16][512][128][3]
    const u16* __restrict__ w1b, const u16* __restrict__ w2b,
    const float* __restrict__ b2,
    float* __restrict__ partial)
{
    __shared__ __align__(16) char smem[54784];
    u16*   ES  = (u16*)smem;             // [256 rows=(i*16+j)][40] : 32 sim ch
    u16*   MT  = (u16*)(smem + 20480);   // per-wave miniT [16][40]
    float* BD  = (float*)(smem + 25600); // bdis stage [16 i][16 j][4]
    u16*   EST = (u16*)(smem + 29696);   // Estage [32 h][16 i][24 j-slot]

    const int tid = threadIdx.x;
    const int lane = tid & 63, wv = tid >> 6;
    const int qd = lane >> 4, ln = lane & 15;
    const int nblk = blockIdx.x;
    const int xcd = nblk & 7, g = nblk >> 3;
    const int b = xcd * 2 + (g & 1);
    const int r2 = g >> 1;
    const int it = r2 >> 2, jq = r2 & 3;
    const int i0 = it * 16;
    const int pidx = (b * 8 + it) * 4 + jq;

    float b2r[4];
#pragma unroll
    for (int ot = 0; ot < 4; ++ot) b2r[ot] = b2[ot * 16 + ln];

    f32x4 oacc[8][2];
#pragma unroll
    for (int a = 0; a < 8; ++a)
#pragma unroll
        for (int c = 0; c < 2; ++c) oacc[a][c] = (f32x4){0.f, 0.f, 0.f, 0.f};
    float dn[4][4] = {};
    float dd[4][3][2] = {};

#pragma clang loop unroll(disable)
    for (int ps = 0; ps < 8; ++ps) {
        const int jg0 = jq * 128 + ps * 16;

        // ---- P1: sim (MFMA) -> ES; stage bdis ----
        {
            const u16* qrow = qk + (size_t)(b * 128 + i0 + ln) * 1024 + qd * 8;
            const u16* crow = cqk + (size_t)(b * 512 + jg0 + ln) * 1024 + qd * 8;
#pragma unroll
            for (int hh = 0; hh < 4; ++hh) {
                const int h0 = wv * 8 + hh * 2;
                bf16x8 a0 = *(const bf16x8*)(qrow + h0 * 32);
                bf16x8 a1 = *(const bf16x8*)(qrow + (h0 + 1) * 32);
                bf16x8 b0 = *(const bf16x8*)(crow + h0 * 32);
                bf16x8 b1 = *(const bf16x8*)(crow + (h0 + 1) * 32);
                f32x4 c0 = (f32x4){0.f, 0.f, 0.f, 0.f}, c1 = c0;
                c0 = MFMA_BF16(a0, b0, c0, 0, 0, 0);
                c1 = MFMA_BF16(a1, b1, c1, 0, 0, 0);
#pragma unroll
                for (int r = 0; r < 4; ++r) {
                    u32 pv = (u32)f2bf(c0[r]) | ((u32)f2bf(c1[r]) << 16);
                    *(u32*)&ES[((qd * 4 + r) * 16 + ln) * 40 + h0] = pv;
                }
            }
        }
        {
            int ii = tid & 15, jj = tid >> 4;
            const float* sp = bdis + ((size_t)(b * 512 + jg0 + jj) * 128 + i0 + ii) * 3;
            float* dp2 = &BD[(ii * 16 + jj) * 4];
            dp2[0] = sp[0]; dp2[1] = sp[1]; dp2[2] = sp[2];
        }
        __syncthreads();

        // ---- P2: per s (i = wv*4+s): MLP1 -> mish -> MLP2 -> exp -> Estage ----
#pragma unroll
        for (int s = 0; s < 4; ++s) {
            const int i_loc = wv * 4 + s;
            bf16x8 af0 = *(const bf16x8*)&ES[(i_loc * 16 + ln) * 40 + qd * 8];
            bf16x8 af1;
            {   // bde channels ARE the A-frag: direct global load
                const float* dp = bde + (((size_t)(b * 512 + jg0 + ln)) * 128 + i0 + i_loc) * 32 + qd * 8;
                float4 a0 = ((const float4*)dp)[0];
                float4 a1 = ((const float4*)dp)[1];
                af1[0] = (short)f2bf(a0.x); af1[1] = (short)f2bf(a0.y);
                af1[2] = (short)f2bf(a0.z); af1[3] = (short)f2bf(a0.w);
                af1[4] = (short)f2bf(a1.x); af1[5] = (short)f2bf(a1.y);
                af1[6] = (short)f2bf(a1.z); af1[7] = (short)f2bf(a1.w);
            }
            f32x4 uacc[4];
#pragma unroll
            for (int ot = 0; ot < 4; ++ot) uacc[ot] = (f32x4){0.f, 0.f, 0.f, 0.f};
            u16* mt = MT + wv * 640;
#pragma unroll
            for (int cg = 0; cg < 4; ++cg) {
                bf16x8 w00 = *(const bf16x8*)(w1b + ((size_t)(cg * 2 + 0) * 64 + lane) * 8);
                bf16x8 w01 = *(const bf16x8*)(w1b + ((size_t)(cg * 2 + 1) * 64 + lane) * 8);
                bf16x8 w10 = *(const bf16x8*)(w1b + ((size_t)(8 + cg * 2 + 0) * 64 + lane) * 8);
                bf16x8 w11 = *(const bf16x8*)(w1b + ((size_t)(8 + cg * 2 + 1) * 64 + lane) * 8);
                f32x4 t0 = (f32x4){0.f, 0.f, 0.f, 0.f}, t1 = t0;
                t0 = MFMA_BF16(af0, w00, t0, 0, 0, 0);
                t0 = MFMA_BF16(af1, w10, t0, 0, 0, 0);
                t1 = MFMA_BF16(af0, w01, t1, 0, 0, 0);
                t1 = MFMA_BF16(af1, w11, t1, 0, 0, 0);
#pragma unroll
                for (int r = 0; r < 4; ++r) {
                    mt[(qd * 4 + r) * 40 + ln]      = f2bf(mishf(t0[r]));
                    mt[(qd * 4 + r) * 40 + 16 + ln] = f2bf(mishf(t1[r]));
                }
                bf16x8 ta = *(const bf16x8*)&mt[ln * 40 + qd * 8];
#pragma unroll
                for (int ot = 0; ot < 4; ++ot) {
                    bf16x8 wf = *(const bf16x8*)(w2b + ((size_t)(cg * 4 + ot) * 64 + lane) * 8);
                    uacc[ot] = MFMA_BF16(ta, wf, uacc[ot], 0, 0, 0);
                }
            }
            float Ev[4][4];
#pragma unroll
            for (int ot = 0; ot < 4; ++ot) {
#pragma unroll
                for (int r = 0; r < 4; ++r) Ev[ot][r] = __expf(uacc[ot][r] + b2r[ot]);
                dn[s][ot] += Ev[ot][0] + Ev[ot][1] + Ev[ot][2] + Ev[ot][3];
            }
            // dis accumulation (bdis broadcast from LDS, same addr across ln)
#pragma unroll
            for (int r = 0; r < 4; ++r) {
                const float* bp = &BD[(i_loc * 16 + qd * 4 + r) * 4];
#pragma unroll
                for (int d = 0; d < 3; ++d) {
                    dd[s][d][0] += Ev[2][r] * bp[d];
                    dd[s][d][1] += Ev[3][r] * bp[d];
                }
            }
            // E head channels -> Estage[h][i][j]
#pragma unroll
            for (int ot = 0; ot < 2; ++ot) {
                const int base = (ot * 16 + ln) * 392 + i_loc * 24 + qd * 4;
                *(u32*)&EST[base]     = (u32)f2bf(Ev[ot][0]) | ((u32)f2bf(Ev[ot][1]) << 16);
                *(u32*)&EST[base + 2] = (u32)f2bf(Ev[ot][2]) | ((u32)f2bf(Ev[ot][3]) << 16);
            }
        }
        __syncthreads();

        // ---- P3: PV via MFMA: A = Estage (K=16 zero-padded), B = cvT ----
#pragma unroll
        for (int hh = 0; hh < 8; ++hh) {
            const int h = wv * 8 + hh;
            bf16x8 af = (bf16x8){0, 0, 0, 0, 0, 0, 0, 0};
            if (qd < 2) af = *(const bf16x8*)&EST[h * 392 + ln * 24 + qd * 8];
#pragma unroll
            for (int nt = 0; nt < 2; ++nt) {
                bf16x8 bfr = (bf16x8){0, 0, 0, 0, 0, 0, 0, 0};
                if (qd < 2)
                    bfr = *(const bf16x8*)(cvT + ((size_t)(b * 1024 + h * 32 + nt * 16 + ln)) * 512 + jg0 + qd * 8);
                oacc[hh][nt] = MFMA_BF16(af, bfr, oacc[hh][nt], 0, 0, 0);
            }
        }
        __syncthreads();
    }

    // ---- epilogue: write partials ----
    float* P = partial + (size_t)pidx * 18944;
#pragma unroll
    for (int hh = 0; hh < 8; ++hh)
#pragma unroll
        for (int nt = 0; nt < 2; ++nt)
#pragma unroll
            for (int r = 0; r < 4; ++r)
                P[(size_t)(qd * 4 + r) * 1024 + (wv * 8 + hh) * 32 + nt * 16 + ln] = oacc[hh][nt][r];
#pragma unroll
    for (int s = 0; s < 4; ++s)
#pragma unroll
        for (int ot = 0; ot < 4; ++ot) {
            float v = dn[s][ot];
            v += __shfl_xor(v, 16, 64);
            v += __shfl_xor(v, 32, 64);
            if (qd == 0) P[16384 + (wv * 4 + s) * 64 + ot * 16 + ln] = v;
        }
#pragma unroll
    for (int s = 0; s < 4; ++s)
#pragma unroll
        for (int d = 0; d < 3; ++d)
#pragma unroll
            for (int o = 0; o < 2; ++o) {
                float v = dd[s][d][o];
                v += __shfl_xor(v, 16, 64);
                v += __shfl_xor(v, 32, 64);
                if (qd == 0) P[17408 + (wv * 4 + s) * 96 + d * 32 + o * 16 + ln] = v;
            }
}

// ---------------------------------------------------------------------------
// finalize: per (b,it): combine 4 jq partials, normalize, Wo epilogue (MFMA),
// dis-MLP. 128 blocks x 256 threads.
// ---------------------------------------------------------------------------
__global__ __launch_bounds__(256, 2) void finalize(
    const float* __restrict__ partial, const u16* __restrict__ WoT,
    const float* __restrict__ bo,
    const float* __restrict__ Wd1, const float* __restrict__ bd1,
    const float* __restrict__ Wd2, const float* __restrict__ bd2,
    float* __restrict__ out0, float* __restrict__ out1)
{
    __shared__ float denomL[1024];
    __shared__ u16 preL[16 * 1032];
    __shared__ float odisL[1536];
    __shared__ float r1L[3072];

    const int tid = threadIdx.x;
    const int f = blockIdx.x;
    const int b = f >> 3, it = f & 7;
    const int row0 = b * 128 + it * 16;
    const float* P0 = partial + (size_t)(f * 4 + 0) * 18944;
    const float* P1 = partial + (size_t)(f * 4 + 1) * 18944;
    const float* P2 = partial + (size_t)(f * 4 + 2) * 18944;
    const float* P3 = partial + (size_t)(f * 4 + 3) * 18944;

    for (int k = tid; k < 1024; k += 256)
        denomL[k] = P0[16384 + k] + P1[16384 + k] + P2[16384 + k] + P3[16384 + k];
    __syncthreads();

    {
        const int h = tid >> 3;
#pragma unroll
        for (int i = 0; i < 16; ++i) {
            float4 a = *(const float4*)&P0[(size_t)i * 1024 + tid * 4];
            float4 bq = *(const float4*)&P1[(size_t)i * 1024 + tid * 4];
            float4 c = *(const float4*)&P2[(size_t)i * 1024 + tid * 4];
            float4 d = *(const float4*)&P3[(size_t)i * 1024 + tid * 4];
            float rdn = 1.f / denomL[i * 64 + h];
            u32 p0 = (u32)f2bf((a.x + bq.x + c.x + d.x) * rdn) | ((u32)f2bf((a.y + bq.y + c.y + d.y) * rdn) << 16);
            u32 p1 = (u32)f2bf((a.z + bq.z + c.z + d.z) * rdn) | ((u32)f2bf((a.w + bq.w + c.w + d.w) * rdn) << 16);
            *(uint2*)(void*)&preL[i * 1032 + tid * 4] = make_uint2(p0, p1);
        }
    }
    for (int idx = tid; idx < 1536; idx += 256) {
        int i = idx / 96, rm = idx % 96, h = rm & 31;
        odisL[idx] = (P0[17408 + idx] + P1[17408 + idx] + P2[17408 + idx] + P3[17408 + idx])
                     / denomL[i * 64 + 32 + h];
    }
    __syncthreads();

    {
        const int lane = tid & 63, wv = tid >> 6;
        const int qd = lane >> 4, ln = lane & 15;
        f32x4 acc[4];
#pragma unroll
        for (int nt = 0; nt < 4; ++nt) acc[nt] = (f32x4){0.f, 0.f, 0.f, 0.f};
#pragma clang loop unroll(disable)
        for (int ks = 0; ks < 32; ++ks) {
            bf16x8 af = *(const bf16x8*)&preL[ln * 1032 + ks * 32 + qd * 8];
#pragma unroll
            for (int nt = 0; nt < 4; ++nt) {
                bf16x8 wf = *(const bf16x8*)(WoT + ((size_t)(wv * 64 + nt * 16 + ln)) * 1024 + ks * 32 + qd * 8);
                acc[nt] = MFMA_BF16(af, wf, acc[nt], 0, 0, 0);
            }
        }
#pragma unroll
        for (int nt = 0; nt < 4; ++nt) {
            int col = wv * 64 + nt * 16 + ln;
            float bv = bo[col];
#pragma unroll
            for (int r = 0; r < 4; ++r)
                out0[(size_t)(row0 + qd * 4 + r) * 256 + col] = acc[nt][r] + bv;
        }
    }

    for (int idx = tid; idx < 3072; idx += 256) {
        int i = idx / 192, rm = idx % 192, d = rm / 64, c = rm & 63;
        float t = bd1[c];
#pragma unroll
        for (int hh = 0; hh < 32; ++hh)
            t += odisL[i * 96 + d * 32 + hh] * Wd1[hh * 64 + c];
        r1L[idx] = mishf(t);
    }
    __syncthreads();
    for (int idx = tid; idx < 1536; idx += 256) {
        int i = idx / 96, rm = idx % 96, d = rm >> 5, h = rm & 31;
        float v = bd2[h];
#pragma unroll
        for (int c = 0; c < 64; ++c)
            v += r1L[i * 192 + d * 64 + c] * Wd2[c * 32 + h];
        out1[(size_t)(row0 + i) * 96 + d * 32 + h] = v;
    }
}

extern "C" void kernel_launch(void* const* d_in, const int* in_sizes, int n_in,
                              void* d_out, int out_size, void* d_ws, size_t ws_size,
                              hipStream_t stream) {
    const float* x    = (const float*)d_in[0];
    const float* ctx  = (const float*)d_in[1];
    const float* bdis = (const float*)d_in[2];
    const float* bde  = (const float*)d_in[3];
    const float* Wqk  = (const float*)d_in[6];
    const float* Wcqk = (const float*)d_in[8];
    const float* Wcv  = (const float*)d_in[9];
    const float* Wm1  = (const float*)d_in[10];
    const float* Wm2  = (const float*)d_in[11];
    const float* bm2  = (const float*)d_in[12];
    const float* Wo   = (const float*)d_in[13];
    const float* bo   = (const float*)d_in[14];
    const float* Wd1  = (const float*)d_in[15];
    const float* bd1  = (const float*)d_in[16];
    const float* Wd2  = (const float*)d_in[17];
    const float* bd2  = (const float*)d_in[18];

    char* ws = (char*)d_ws;
    u16* qk_ws  = (u16*)(ws);                       // 4 MB
    u16* cqk_ws = (u16*)(ws + 4194304);             // 16 MB
    u16* cvT_ws = (u16*)(ws + 20971520);            // 16 MB
    u16* w1b    = (u16*)(ws + 37748736);            // 16 KB
    u16* w2b    = (u16*)(ws + 37765120);            // 16 KB
    u16* WoT    = (u16*)(ws + 37781504);            // 512 KB
    float* part = (float*)(ws + 38305792);          // 512*18944*4 = 38.8 MB
    u16* cv_rm  = (u16*)(ws + 38305792);            // 16 MB overlay (dead before part is written)

    float* out0 = (float*)d_out;
    float* out1 = out0 + (size_t)2048 * 256;

    const float SCALE = 0.17677669529663687f;       // 32^-0.5, folded into qk

    prep<<<257, 256, 0, stream>>>(Wo, Wm1, Wm2, WoT, w1b, w2b);
    gemm_mfma<<<dim3(16, 16), 256, 0, stream>>>(x,   Wqk,  qk_ws,  2048, 1024, 256, SCALE);
    gemm_mfma<<<dim3(16, 64), 256, 0, stream>>>(ctx, Wcqk, cqk_ws, 8192, 1024, 256, 1.0f);
    gemm_mfma<<<dim3(16, 64), 256, 0, stream>>>(ctx, Wcv,  cv_rm,  8192, 1024, 256, 1.0f);
    transpose_cv<<<dim3(16, 8, 16), 256, 0, stream>>>(cv_rm, cvT_ws);
    attn4<<<512, 256, 0, stream>>>(qk_ws, cqk_ws, cvT_ws, bde, bdis, w1b, w2b, bm2, part);
    finalize<<<128, 256, 0, stream>>>(part, WoT, bo, Wd1, bd1, Wd2, bd2, out0, out1);
}

// Round 6
// 565.164 us; speedup vs baseline: 1.4091x; 1.4091x over previous
//
#include <hip/hip_runtime.h>

typedef unsigned short u16;
typedef unsigned int   u32;
typedef __attribute__((ext_vector_type(8))) short bf16x8;
typedef __attribute__((ext_vector_type(4))) float f32x4;

#define MFMA_BF16 __builtin_amdgcn_mfma_f32_16x16x32_bf16

__device__ __forceinline__ float bf2f(u16 v) {
    u32 x = ((u32)v) << 16;
    return __builtin_bit_cast(float, x);
}
__device__ __forceinline__ float bflo(u32 u) { return __builtin_bit_cast(float, u << 16); }
__device__ __forceinline__ float bfhi(u32 u) { return __builtin_bit_cast(float, u & 0xffff0000u); }
__device__ __forceinline__ u16 f2bf(float f) {
    u32 x = __builtin_bit_cast(u32, f);
    u32 r = (x + 0x7fffu + ((x >> 16) & 1u)) >> 16;
    return (u16)r;
}
__device__ __forceinline__ float mishf(float x) {
    float p = 1.f + __expf(x);
    float q = p * p;
    float r = (q - 1.f) / (q + 1.f);
    return (x > 20.f) ? x : x * r;
}

// ---------------------------------------------------------------------------
// MFMA GEMM: C[M,N] = bf16( A[M,K] @ W[K,N] * scale ), fp32 in, bf16 out.
// Tile 128M x 64N, K-step 32, 256 thr. M % 128 == 0, N = 1024, K = 256.
// ---------------------------------------------------------------------------
__global__ __launch_bounds__(256) void gemm_mfma(
    const float* __restrict__ A, const float* __restrict__ W, u16* __restrict__ C,
    int M, int N, int K, float scale)
{
    __shared__ u16 As[128 * 40];
    __shared__ u16 Bf[4 * 64 * 8];

    const int tid = threadIdx.x;
    const int lane = tid & 63, wv = tid >> 6;
    const int qd = lane >> 4, ln = lane & 15;
    const int m0 = blockIdx.y * 128, n0 = blockIdx.x * 64;

    f32x4 acc[2][4];
#pragma unroll
    for (int a = 0; a < 2; ++a)
#pragma unroll
        for (int nt = 0; nt < 4; ++nt) acc[a][nt] = (f32x4){0.f, 0.f, 0.f, 0.f};

    for (int k0 = 0; k0 < K; k0 += 32) {
        {
            int r = tid >> 1, kh = (tid & 1) * 16;
            const float* ap = A + (size_t)(m0 + r) * K + k0 + kh;
            float4 a0 = ((const float4*)ap)[0];
            float4 a1 = ((const float4*)ap)[1];
            float4 a2 = ((const float4*)ap)[2];
            float4 a3 = ((const float4*)ap)[3];
            uint4 p0, p1;
            p0.x = (u32)f2bf(a0.x) | ((u32)f2bf(a0.y) << 16);
            p0.y = (u32)f2bf(a0.z) | ((u32)f2bf(a0.w) << 16);
            p0.z = (u32)f2bf(a1.x) | ((u32)f2bf(a1.y) << 16);
            p0.w = (u32)f2bf(a1.z) | ((u32)f2bf(a1.w) << 16);
            p1.x = (u32)f2bf(a2.x) | ((u32)f2bf(a2.y) << 16);
            p1.y = (u32)f2bf(a2.z) | ((u32)f2bf(a2.w) << 16);
            p1.z = (u32)f2bf(a3.x) | ((u32)f2bf(a3.y) << 16);
            p1.w = (u32)f2bf(a3.z) | ((u32)f2bf(a3.w) << 16);
            *(uint4*)&As[r * 40 + kh]     = p0;
            *(uint4*)&As[r * 40 + kh + 8] = p1;
        }
        {
            int nt = tid >> 6, q = (tid >> 4) & 3, nn = tid & 15;
            const float* wp = W + (size_t)(k0 + q * 8) * N + n0 + nt * 16 + nn;
            bf16x8 v;
#pragma unroll
            for (int j = 0; j < 8; ++j) v[j] = (short)f2bf(wp[(size_t)j * N]);
            *(bf16x8*)&Bf[tid * 8] = v;
        }
        __syncthreads();
        bf16x8 af0 = *(const bf16x8*)&As[(wv * 32 + ln) * 40 + qd * 8];
        bf16x8 af1 = *(const bf16x8*)&As[(wv * 32 + 16 + ln) * 40 + qd * 8];
#pragma unroll
        for (int nt = 0; nt < 4; ++nt) {
            bf16x8 bfr = *(const bf16x8*)&Bf[(nt * 64 + lane) * 8];
            acc[0][nt] = MFMA_BF16(af0, bfr, acc[0][nt], 0, 0, 0);
            acc[1][nt] = MFMA_BF16(af1, bfr, acc[1][nt], 0, 0, 0);
        }
        __syncthreads();
    }
#pragma unroll
    for (int a = 0; a < 2; ++a)
#pragma unroll
        for (int nt = 0; nt < 4; ++nt)
#pragma unroll
            for (int r = 0; r < 4; ++r)
                C[(size_t)(m0 + wv * 32 + a * 16 + qd * 4 + r) * N + n0 + nt * 16 + ln] =
                    f2bf(acc[a][nt][r] * scale);
}

// ---------------------------------------------------------------------------
// transpose cv[b*512+j][1024 ch] -> cvT[(b*1024+ch)*512 + j]. 64x64 tiles.
// ---------------------------------------------------------------------------
__global__ __launch_bounds__(256) void transpose_cv(
    const u16* __restrict__ cv, u16* __restrict__ cvT)
{
    __shared__ u16 T[64 * 80];
    const int tid = threadIdx.x;
    const int ct = blockIdx.x * 64, jt = blockIdx.y * 64, b = blockIdx.z;
    {
        int j_l = tid >> 2, seg = tid & 3;
        const u16* src = cv + (size_t)(b * 512 + jt + j_l) * 1024 + ct + seg * 16;
        uint4 v0 = ((const uint4*)src)[0];
        uint4 v1 = ((const uint4*)src)[1];
        u16* tp = &T[seg * 16 * 80 + j_l];
        tp[0*80] = (u16)(v0.x & 0xffff); tp[1*80] = (u16)(v0.x >> 16);
        tp[2*80] = (u16)(v0.y & 0xffff); tp[3*80] = (u16)(v0.y >> 16);
        tp[4*80] = (u16)(v0.z & 0xffff); tp[5*80] = (u16)(v0.z >> 16);
        tp[6*80] = (u16)(v0.w & 0xffff); tp[7*80] = (u16)(v0.w >> 16);
        tp[8*80] = (u16)(v1.x & 0xffff); tp[9*80] = (u16)(v1.x >> 16);
        tp[10*80] = (u16)(v1.y & 0xffff); tp[11*80] = (u16)(v1.y >> 16);
        tp[12*80] = (u16)(v1.z & 0xffff); tp[13*80] = (u16)(v1.z >> 16);
        tp[14*80] = (u16)(v1.w & 0xffff); tp[15*80] = (u16)(v1.w >> 16);
    }
    __syncthreads();
    {
        int ch_l = tid >> 2, sg = tid & 3;
        u16* dst = cvT + (size_t)(b * 1024 + ct + ch_l) * 512 + jt + sg * 16;
        ((uint4*)dst)[0] = *(const uint4*)&T[ch_l * 80 + sg * 16];
        ((uint4*)dst)[1] = *(const uint4*)&T[ch_l * 80 + sg * 16 + 8];
    }
}

// ---------------------------------------------------------------------------
// Prep: WoT[col][k] bf16; W1/W2 swizzled to MFMA B-frag order.
// ---------------------------------------------------------------------------
__global__ __launch_bounds__(256) void prep(
    const float* __restrict__ Wo, const float* __restrict__ W1, const float* __restrict__ W2,
    u16* __restrict__ WoT, u16* __restrict__ w1b, u16* __restrict__ w2b)
{
    const int bb = blockIdx.x, t = threadIdx.x;
    if (bb < 256) {
#pragma unroll
        for (int kk = 0; kk < 4; ++kk)
            WoT[(size_t)t * 1024 + bb * 4 + kk] = f2bf(Wo[(size_t)(bb * 4 + kk) * 256 + t]);
    } else {
        for (int u = 0; u < 32; ++u) {        // W1: frag f = ks*8+nt
            int idx = t + 256 * u;
            int j = idx & 7, lane = (idx >> 3) & 63, f = idx >> 9;
            int n = lane & 15, q = lane >> 4, ntc = f & 7, ks = f >> 3;
            w1b[idx] = f2bf(W1[(ks * 32 + q * 8 + j) * 128 + ntc * 16 + n]);
        }
        for (int u = 0; u < 32; ++u) {        // W2: frag f = ks*4+ot
            int idx = t + 256 * u;
            int j = idx & 7, lane = (idx >> 3) & 63, f = idx >> 9;
            int n = lane & 15, q = lane >> 4, ot = f & 3, ks = f >> 2;
            w2b[idx] = f2bf(W2[(ks * 32 + q * 8 + j) * 64 + ot * 16 + n]);
        }
    }
}

// ---------------------------------------------------------------------------
// attn5: attn4 structure, spill-free: __launch_bounds__(256,1) frees the
// register allocator (VGPR cap was 128 -> scratch spill, 650 MB/dispatch);
// W1 frags LDS-resident again; qk frags register-hoisted across passes.
// block = (b, i-tile 16, j-quarter 128), XCD-swizzled. 8 passes of 16 j.
// ---------------------------------------------------------------------------
__global__ __launch_bounds__(256, 1) void attn5(
    const u16* __restrict__ qk,      // [2048][1024] bf16 (scale folded)
    const u16* __restrict__ cqk,     // [8192][1024] bf16
    const u16* __restrict__ cvT,     // [16][1024][512] bf16
    const float* __restrict__ bde,   // [16][512][128][32]
    const float* __restrict__ bdis,  // [16][512][128][3]
    const u16* __restrict__ w1b, const u16* __restrict__ w2b,
    const float* __restrict__ b2,
    float* __restrict__ partial)
{
    __shared__ __align__(16) char smem[62976];
    u16*   ES  = (u16*)smem;             // [256 rows=(i*16+j)][40] : 32 sim ch
    u16*   MT  = (u16*)(smem + 20480);   // per-wave miniT [16][40]
    float* BD  = (float*)(smem + 25600); // bdis stage [16 i][16 j][4]
    u16*   EST = (u16*)(smem + 29696);   // Estage [32 h][16 i][24 j-slot]
    u16*   W1B = (u16*)(smem + 54784);   // 8192 B W1 frags

    const int tid = threadIdx.x;
    const int lane = tid & 63, wv = tid >> 6;
    const int qd = lane >> 4, ln = lane & 15;
    const int nblk = blockIdx.x;
    const int xcd = nblk & 7, g = nblk >> 3;
    const int b = xcd * 2 + (g & 1);
    const int r2 = g >> 1;
    const int it = r2 >> 2, jq = r2 & 3;
    const int i0 = it * 16;
    const int pidx = (b * 8 + it) * 4 + jq;

    for (int k = tid; k < 4096; k += 256) ((u32*)W1B)[k] = ((const u32*)w1b)[k];

    float b2r[4];
#pragma unroll
    for (int ot = 0; ot < 4; ++ot) b2r[ot] = b2[ot * 16 + ln];

    // qk A-frags: registers for the whole kernel (same i-tile every pass)
    bf16x8 qkf[8];
#pragma unroll
    for (int hh = 0; hh < 8; ++hh) {
        int h = wv * 8 + hh;
        qkf[hh] = *(const bf16x8*)(qk + ((size_t)(b * 128 + i0 + ln)) * 1024 + h * 32 + qd * 8);
    }

    f32x4 oacc[8][2];
#pragma unroll
    for (int a = 0; a < 8; ++a)
#pragma unroll
        for (int c = 0; c < 2; ++c) oacc[a][c] = (f32x4){0.f, 0.f, 0.f, 0.f};
    float dn[4][4] = {};
    float dd[4][3][2] = {};

    __syncthreads();

#pragma clang loop unroll(disable)
    for (int ps = 0; ps < 8; ++ps) {
        const int jg0 = jq * 128 + ps * 16;

        // ---- P1: sim (MFMA) -> ES; stage bdis ----
        {
            const u16* crow = cqk + (size_t)(b * 512 + jg0 + ln) * 1024 + qd * 8;
#pragma unroll
            for (int hh = 0; hh < 4; ++hh) {
                const int h0 = wv * 8 + hh * 2;
                bf16x8 b0 = *(const bf16x8*)(crow + h0 * 32);
                bf16x8 b1 = *(const bf16x8*)(crow + (h0 + 1) * 32);
                f32x4 c0 = (f32x4){0.f, 0.f, 0.f, 0.f}, c1 = c0;
                c0 = MFMA_BF16(qkf[hh * 2],     b0, c0, 0, 0, 0);
                c1 = MFMA_BF16(qkf[hh * 2 + 1], b1, c1, 0, 0, 0);
#pragma unroll
                for (int r = 0; r < 4; ++r) {
                    u32 pv = (u32)f2bf(c0[r]) | ((u32)f2bf(c1[r]) << 16);
                    *(u32*)&ES[((qd * 4 + r) * 16 + ln) * 40 + h0] = pv;
                }
            }
        }
        {
            int ii = tid & 15, jj = tid >> 4;
            const float* sp = bdis + ((size_t)(b * 512 + jg0 + jj) * 128 + i0 + ii) * 3;
            float* dp2 = &BD[(ii * 16 + jj) * 4];
            dp2[0] = sp[0]; dp2[1] = sp[1]; dp2[2] = sp[2];
        }
        __syncthreads();

        // ---- P2: per s (i = wv*4+s): MLP1 -> mish -> MLP2 -> exp -> Estage ----
#pragma unroll
        for (int s = 0; s < 4; ++s) {
            const int i_loc = wv * 4 + s;
            bf16x8 af0 = *(const bf16x8*)&ES[(i_loc * 16 + ln) * 40 + qd * 8];
            bf16x8 af1;
            {   // bde channels ARE the A-frag: direct global load
                const float* dp = bde + (((size_t)(b * 512 + jg0 + ln)) * 128 + i0 + i_loc) * 32 + qd * 8;
                float4 a0 = ((const float4*)dp)[0];
                float4 a1 = ((const float4*)dp)[1];
                af1[0] = (short)f2bf(a0.x); af1[1] = (short)f2bf(a0.y);
                af1[2] = (short)f2bf(a0.z); af1[3] = (short)f2bf(a0.w);
                af1[4] = (short)f2bf(a1.x); af1[5] = (short)f2bf(a1.y);
                af1[6] = (short)f2bf(a1.z); af1[7] = (short)f2bf(a1.w);
            }
            f32x4 uacc[4];
#pragma unroll
            for (int ot = 0; ot < 4; ++ot) uacc[ot] = (f32x4){0.f, 0.f, 0.f, 0.f};
            u16* mt = MT + wv * 640;
#pragma unroll
            for (int cg = 0; cg < 4; ++cg) {
                bf16x8 w00 = *(const bf16x8*)&W1B[((cg * 2 + 0) * 64 + lane) * 8];
                bf16x8 w01 = *(const bf16x8*)&W1B[((cg * 2 + 1) * 64 + lane) * 8];
                bf16x8 w10 = *(const bf16x8*)&W1B[((8 + cg * 2 + 0) * 64 + lane) * 8];
                bf16x8 w11 = *(const bf16x8*)&W1B[((8 + cg * 2 + 1) * 64 + lane) * 8];
                f32x4 t0 = (f32x4){0.f, 0.f, 0.f, 0.f}, t1 = t0;
                t0 = MFMA_BF16(af0, w00, t0, 0, 0, 0);
                t0 = MFMA_BF16(af1, w10, t0, 0, 0, 0);
                t1 = MFMA_BF16(af0, w01, t1, 0, 0, 0);
                t1 = MFMA_BF16(af1, w11, t1, 0, 0, 0);
#pragma unroll
                for (int r = 0; r < 4; ++r) {
                    mt[(qd * 4 + r) * 40 + ln]      = f2bf(mishf(t0[r]));
                    mt[(qd * 4 + r) * 40 + 16 + ln] = f2bf(mishf(t1[r]));
                }
                bf16x8 ta = *(const bf16x8*)&mt[ln * 40 + qd * 8];
#pragma unroll
                for (int ot = 0; ot < 4; ++ot) {
                    bf16x8 wf = *(const bf16x8*)(w2b + ((size_t)(cg * 4 + ot) * 64 + lane) * 8);
                    uacc[ot] = MFMA_BF16(ta, wf, uacc[ot], 0, 0, 0);
                }
            }
            float Ev[4][4];
#pragma unroll
            for (int ot = 0; ot < 4; ++ot) {
#pragma unroll
                for (int r = 0; r < 4; ++r) Ev[ot][r] = __expf(uacc[ot][r] + b2r[ot]);
                dn[s][ot] += Ev[ot][0] + Ev[ot][1] + Ev[ot][2] + Ev[ot][3];
            }
#pragma unroll
            for (int r = 0; r < 4; ++r) {
                const float* bp = &BD[(i_loc * 16 + qd * 4 + r) * 4];
#pragma unroll
                for (int d = 0; d < 3; ++d) {
                    dd[s][d][0] += Ev[2][r] * bp[d];
                    dd[s][d][1] += Ev[3][r] * bp[d];
                }
            }
#pragma unroll
            for (int ot = 0; ot < 2; ++ot) {
                const int base = (ot * 16 + ln) * 392 + i_loc * 24 + qd * 4;
                *(u32*)&EST[base]     = (u32)f2bf(Ev[ot][0]) | ((u32)f2bf(Ev[ot][1]) << 16);
                *(u32*)&EST[base + 2] = (u32)f2bf(Ev[ot][2]) | ((u32)f2bf(Ev[ot][3]) << 16);
            }
        }
        __syncthreads();

        // ---- P3: PV via MFMA: A = Estage (K=16 zero-padded), B = cvT ----
#pragma unroll
        for (int hh = 0; hh < 8; ++hh) {
            const int h = wv * 8 + hh;
            bf16x8 af = (bf16x8){0, 0, 0, 0, 0, 0, 0, 0};
            if (qd < 2) af = *(const bf16x8*)&EST[h * 392 + ln * 24 + qd * 8];
#pragma unroll
            for (int nt = 0; nt < 2; ++nt) {
                bf16x8 bfr = (bf16x8){0, 0, 0, 0, 0, 0, 0, 0};
                if (qd < 2)
                    bfr = *(const bf16x8*)(cvT + ((size_t)(b * 1024 + h * 32 + nt * 16 + ln)) * 512 + jg0 + qd * 8);
                oacc[hh][nt] = MFMA_BF16(af, bfr, oacc[hh][nt], 0, 0, 0);
            }
        }
        __syncthreads();
    }

    // ---- epilogue: write partials ----
    float* P = partial + (size_t)pidx * 18944;
#pragma unroll
    for (int hh = 0; hh < 8; ++hh)
#pragma unroll
        for (int nt = 0; nt < 2; ++nt)
#pragma unroll
            for (int r = 0; r < 4; ++r)
                P[(size_t)(qd * 4 + r) * 1024 + (wv * 8 + hh) * 32 + nt * 16 + ln] = oacc[hh][nt][r];
#pragma unroll
    for (int s = 0; s < 4; ++s)
#pragma unroll
        for (int ot = 0; ot < 4; ++ot) {
            float v = dn[s][ot];
            v += __shfl_xor(v, 16, 64);
            v += __shfl_xor(v, 32, 64);
            if (qd == 0) P[16384 + (wv * 4 + s) * 64 + ot * 16 + ln] = v;
        }
#pragma unroll
    for (int s = 0; s < 4; ++s)
#pragma unroll
        for (int d = 0; d < 3; ++d)
#pragma unroll
            for (int o = 0; o < 2; ++o) {
                float v = dd[s][d][o];
                v += __shfl_xor(v, 16, 64);
                v += __shfl_xor(v, 32, 64);
                if (qd == 0) P[17408 + (wv * 4 + s) * 96 + d * 32 + o * 16 + ln] = v;
            }
}

// ---------------------------------------------------------------------------
// finalize: per (b,it): combine 4 jq partials, normalize, Wo epilogue (MFMA),
// dis-MLP. 128 blocks x 256 threads.
// ---------------------------------------------------------------------------
__global__ __launch_bounds__(256, 2) void finalize(
    const float* __restrict__ partial, const u16* __restrict__ WoT,
    const float* __restrict__ bo,
    const float* __restrict__ Wd1, const float* __restrict__ bd1,
    const float* __restrict__ Wd2, const float* __restrict__ bd2,
    float* __restrict__ out0, float* __restrict__ out1)
{
    __shared__ float denomL[1024];
    __shared__ u16 preL[16 * 1032];
    __shared__ float odisL[1536];
    __shared__ float r1L[3072];

    const int tid = threadIdx.x;
    const int f = blockIdx.x;
    const int b = f >> 3, it = f & 7;
    const int row0 = b * 128 + it * 16;
    const float* P0 = partial + (size_t)(f * 4 + 0) * 18944;
    const float* P1 = partial + (size_t)(f * 4 + 1) * 18944;
    const float* P2 = partial + (size_t)(f * 4 + 2) * 18944;
    const float* P3 = partial + (size_t)(f * 4 + 3) * 18944;

    for (int k = tid; k < 1024; k += 256)
        denomL[k] = P0[16384 + k] + P1[16384 + k] + P2[16384 + k] + P3[16384 + k];
    __syncthreads();

    {
        const int h = tid >> 3;
#pragma unroll
        for (int i = 0; i < 16; ++i) {
            float4 a = *(const float4*)&P0[(size_t)i * 1024 + tid * 4];
            float4 bq = *(const float4*)&P1[(size_t)i * 1024 + tid * 4];
            float4 c = *(const float4*)&P2[(size_t)i * 1024 + tid * 4];
            float4 d = *(const float4*)&P3[(size_t)i * 1024 + tid * 4];
            float rdn = 1.f / denomL[i * 64 + h];
            u32 p0 = (u32)f2bf((a.x + bq.x + c.x + d.x) * rdn) | ((u32)f2bf((a.y + bq.y + c.y + d.y) * rdn) << 16);
            u32 p1 = (u32)f2bf((a.z + bq.z + c.z + d.z) * rdn) | ((u32)f2bf((a.w + bq.w + c.w + d.w) * rdn) << 16);
            *(uint2*)(void*)&preL[i * 1032 + tid * 4] = make_uint2(p0, p1);
        }
    }
    for (int idx = tid; idx < 1536; idx += 256) {
        int i = idx / 96, rm = idx % 96, h = rm & 31;
        odisL[idx] = (P0[17408 + idx] + P1[17408 + idx] + P2[17408 + idx] + P3[17408 + idx])
                     / denomL[i * 64 + 32 + h];
    }
    __syncthreads();

    {
        const int lane = tid & 63, wv = tid >> 6;
        const int qd = lane >> 4, ln = lane & 15;
        f32x4 acc[4];
#pragma unroll
        for (int nt = 0; nt < 4; ++nt) acc[nt] = (f32x4){0.f, 0.f, 0.f, 0.f};
#pragma clang loop unroll(disable)
        for (int ks = 0; ks < 32; ++ks) {
            bf16x8 af = *(const bf16x8*)&preL[ln * 1032 + ks * 32 + qd * 8];
#pragma unroll
            for (int nt = 0; nt < 4; ++nt) {
                bf16x8 wf = *(const bf16x8*)(WoT + ((size_t)(wv * 64 + nt * 16 + ln)) * 1024 + ks * 32 + qd * 8);
                acc[nt] = MFMA_BF16(af, wf, acc[nt], 0, 0, 0);
            }
        }
#pragma unroll
        for (int nt = 0; nt < 4; ++nt) {
            int col = wv * 64 + nt * 16 + ln;
            float bv = bo[col];
#pragma unroll
            for (int r = 0; r < 4; ++r)
                out0[(size_t)(row0 + qd * 4 + r) * 256 + col] = acc[nt][r] + bv;
        }
    }

    for (int idx = tid; idx < 3072; idx += 256) {
        int i = idx / 192, rm = idx % 192, d = rm / 64, c = rm & 63;
        float t = bd1[c];
#pragma unroll
        for (int hh = 0; hh < 32; ++hh)
            t += odisL[i * 96 + d * 32 + hh] * Wd1[hh * 64 + c];
        r1L[idx] = mishf(t);
    }
    __syncthreads();
    for (int idx = tid; idx < 1536; idx += 256) {
        int i = idx / 96, rm = idx % 96, d = rm >> 5, h = rm & 31;
        float v = bd2[h];
#pragma unroll
        for (int c = 0; c < 64; ++c)
            v += r1L[i * 192 + d * 64 + c] * Wd2[c * 32 + h];
        out1[(size_t)(row0 + i) * 96 + d * 32 + h] = v;
    }
}

extern "C" void kernel_launch(void* const* d_in, const int* in_sizes, int n_in,
                              void* d_out, int out_size, void* d_ws, size_t ws_size,
                              hipStream_t stream) {
    const float* x    = (const float*)d_in[0];
    const float* ctx  = (const float*)d_in[1];
    const float* bdis = (const float*)d_in[2];
    const float* bde  = (const float*)d_in[3];
    const float* Wqk  = (const float*)d_in[6];
    const float* Wcqk = (const float*)d_in[8];
    const float* Wcv  = (const float*)d_in[9];
    const float* Wm1  = (const float*)d_in[10];
    const float* Wm2  = (const float*)d_in[11];
    const float* bm2  = (const float*)d_in[12];
    const float* Wo   = (const float*)d_in[13];
    const float* bo   = (const float*)d_in[14];
    const float* Wd1  = (const float*)d_in[15];
    const float* bd1  = (const float*)d_in[16];
    const float* Wd2  = (const float*)d_in[17];
    const float* bd2  = (const float*)d_in[18];

    char* ws = (char*)d_ws;
    u16* qk_ws  = (u16*)(ws);                       // 4 MB
    u16* cqk_ws = (u16*)(ws + 4194304);             // 16 MB
    u16* cvT_ws = (u16*)(ws + 20971520);            // 16 MB
    u16* w1b    = (u16*)(ws + 37748736);            // 16 KB
    u16* w2b    = (u16*)(ws + 37765120);            // 16 KB
    u16* WoT    = (u16*)(ws + 37781504);            // 512 KB
    float* part = (float*)(ws + 38305792);          // 512*18944*4 = 38.8 MB
    u16* cv_rm  = (u16*)(ws + 38305792);            // 16 MB overlay (dead before part)

    float* out0 = (float*)d_out;
    float* out1 = out0 + (size_t)2048 * 256;

    const float SCALE = 0.17677669529663687f;       // 32^-0.5, folded into qk

    prep<<<257, 256, 0, stream>>>(Wo, Wm1, Wm2, WoT, w1b, w2b);
    gemm_mfma<<<dim3(16, 16), 256, 0, stream>>>(x,   Wqk,  qk_ws,  2048, 1024, 256, SCALE);
    gemm_mfma<<<dim3(16, 64), 256, 0, stream>>>(ctx, Wcqk, cqk_ws, 8192, 1024, 256, 1.0f);
    gemm_mfma<<<dim3(16, 64), 256, 0, stream>>>(ctx, Wcv,  cv_rm,  8192, 1024, 256, 1.0f);
    transpose_cv<<<dim3(16, 8, 16), 256, 0, stream>>>(cv_rm, cvT_ws);
    attn5<<<512, 256, 0, stream>>>(qk_ws, cqk_ws, cvT_ws, bde, bdis, w1b, w2b, bm2, part);
    finalize<<<128, 256, 0, stream>>>(part, WoT, bo, Wd1, bd1, Wd2, bd2, out0, out1);
}